// Round 1
// 238.743 us; speedup vs baseline: 1.1020x; 1.1020x over previous
//
#include <hip/hip_runtime.h>
#include <math.h>

#define NEG_HUGE -1e30f
constexpr int B_ = 64, H_ = 128, C_ = 1024, Q_ = 128;

typedef __bf16 bf16x8 __attribute__((ext_vector_type(8)));
typedef float f32x4 __attribute__((ext_vector_type(4)));
typedef short short8 __attribute__((ext_vector_type(8)));
typedef short short4s __attribute__((ext_vector_type(4)));

__device__ __forceinline__ float bs2f(short s) {
  unsigned u = ((unsigned)(unsigned short)s) << 16;
  float f; __builtin_memcpy(&f, &u, 4); return f;
}
__device__ __forceinline__ short f2bs(float f) {
  unsigned u; __builtin_memcpy(&u, &f, 4);
  u = (u + 0x7fffu + ((u >> 16) & 1u)) >> 16;
  return (short)u;
}
// non-temporal float4 store (out is write-once, never re-read this launch)
__device__ __forceinline__ void nts4(float* p, float4 v) {
  f32x4 x; x[0] = v.x; x[1] = v.y; x[2] = v.z; x[3] = v.w;
  __builtin_nontemporal_store(x, (f32x4*)p);
}

// ---------------------------------------------------------------------------
// kTc: cT[b][c][h] (bf16) = cin[b][h][c]; also s0 partials over its h-block.
// grid (16,2,B), block 256.
// ---------------------------------------------------------------------------
__global__ __launch_bounds__(256) void kTc(const float* __restrict__ cin,
                                           const float* __restrict__ ctxw,
                                           short* __restrict__ cT,
                                           float* __restrict__ s0p) {
  __shared__ float T[64 * 69];
  const int t = threadIdx.x;
  const int c0 = blockIdx.x * 64, h0 = blockIdx.y * 64, b = blockIdx.z;
  {
    const int row = t >> 2, off = t & 3;
    const float* src = cin + (b * H_ + h0 + row) * C_ + c0;
#pragma unroll
    for (int j = 0; j < 4; ++j) {
      float4 v = *(const float4*)&src[off * 16 + j * 4];
      int cbase = off * 16 + j * 4;
      T[row * 69 + cbase + 0] = v.x;
      T[row * 69 + cbase + 1] = v.y;
      T[row * 69 + cbase + 2] = v.z;
      T[row * 69 + cbase + 3] = v.w;
    }
  }
  __syncthreads();
  {
    const int c = t >> 2, offh = t & 3;
    short* dst = cT + (b * C_ + c0 + c) * H_ + h0;
#pragma unroll
    for (int j = 0; j < 4; ++j) {
      int hs = offh * 16 + j * 4;
      short4s v;
      v[0] = f2bs(T[(hs + 0) * 69 + c]);
      v[1] = f2bs(T[(hs + 1) * 69 + c]);
      v[2] = f2bs(T[(hs + 2) * 69 + c]);
      v[3] = f2bs(T[(hs + 3) * 69 + c]);
      *(short4s*)&dst[hs] = v;
    }
  }
  if (t < 64) {  // s0 partial for this h-block: sum_h c[h][c]*ctxw[h]
    float acc = 0.f;
#pragma unroll 8
    for (int h = 0; h < 64; ++h) acc += T[h * 69 + t] * ctxw[h0 + h];
    s0p[blockIdx.y * (B_ * C_) + b * C_ + c0 + t] = acc;
  }
}

// ---------------------------------------------------------------------------
// kq: qTw[b][q][h] = qin*cqw (bf16); qbf[b][h][q] = qin (bf16);
// s1m[b][q] = q.qw + qmask.  grid (2,B), block 256.
// ---------------------------------------------------------------------------
__global__ __launch_bounds__(256) void kq(const float* __restrict__ qin,
                                          const float* __restrict__ qw,
                                          const float* __restrict__ cqw,
                                          const float* __restrict__ qmask,
                                          short* __restrict__ qTw,
                                          short* __restrict__ qbf,
                                          float* __restrict__ s1m) {
  __shared__ float T[64 * 130];  // [q-local][h]
  const int t = threadIdx.x;
  const int q0 = blockIdx.x * 64, b = blockIdx.y;
#pragma unroll
  for (int p = 0; p < 8; ++p) {
    int fidx = t + 256 * p;
    int h = fidx >> 4, seg = fidx & 15;
    float4 v = *(const float4*)&qin[(b * H_ + h) * Q_ + q0 + seg * 4];
    T[(seg * 4 + 0) * 130 + h] = v.x;
    T[(seg * 4 + 1) * 130 + h] = v.y;
    T[(seg * 4 + 2) * 130 + h] = v.z;
    T[(seg * 4 + 3) * 130 + h] = v.w;
    short4s o; o[0] = f2bs(v.x); o[1] = f2bs(v.y); o[2] = f2bs(v.z); o[3] = f2bs(v.w);
    *(short4s*)&qbf[(b * H_ + h) * Q_ + q0 + seg * 4] = o;
  }
  __syncthreads();
  if (t < 64) {
    float acc = 0.f;
#pragma unroll 8
    for (int h = 0; h < 128; ++h) acc += T[t * 130 + h] * qw[h];
    float qm = (qmask[b * Q_ + q0 + t] > 0.f) ? 0.f : NEG_HUGE;
    s1m[b * Q_ + q0 + t] = acc + qm;
  }
  {
    const int q = t >> 2, off = t & 3;
    short* dst = qTw + (b * Q_ + q0 + q) * H_;
#pragma unroll
    for (int j = 0; j < 4; ++j) {
      int hbv = off * 32 + j * 8;
      short8 v;
#pragma unroll
      for (int i = 0; i < 8; ++i) v[i] = f2bs(T[q * 130 + hbv + i] * cqw[hbv + i]);
      *(short8*)&dst[hbv] = v;
    }
  }
}

// ---------------------------------------------------------------------------
// k1: MFMA s2-tile (128c x 128q), fused row softmax -> a_att bf16,
// fused col partial stats + eP bf16 (transposed).  grid (8, B), block 256.
// Exp-reduced: row-exp computed ONCE into acc; column side reconstructed as
// rowexp * exp((cs0+rm) - (s1v+mpv)).  128 exps/thread vs 256 before.
// ---------------------------------------------------------------------------
__global__ __launch_bounds__(256) void k1_mfma(
    const short* __restrict__ cT, const short* __restrict__ qTw,
    const float* __restrict__ s1m, const float* __restrict__ cmask,
    const float* __restrict__ s0p,
    short* __restrict__ a_att, short* __restrict__ ePT,
    float* __restrict__ pcm, float* __restrict__ pcs) {
  __shared__ __align__(16) char uni[34816];
  __shared__ float s1mL[128], scolL[128], pw[512], mpL[128];
  short* AL = (short*)uni;            // [128][40] bf16
  short* BL = (short*)(uni + 10240);  // [128][40] bf16
  short* RP = (short*)uni;            // [128][136] bf16 (after K-loop)

  const int t = threadIdx.x;
  const int w = t >> 6, l = t & 63, quad = l >> 4, lcol = l & 15;
  const int bx = blockIdx.x, b = blockIdx.y, c0 = bx * 128;

  if (t < 128) {
    s1mL[t] = s1m[b * Q_ + t];
    float cm = (cmask[b * C_ + c0 + t] > 0.f) ? 0.f : NEG_HUGE;
    scolL[t] = cm + s0p[b * C_ + c0 + t] + s0p[B_ * C_ + b * C_ + c0 + t];
  }

  f32x4 acc[2][8];
#pragma unroll
  for (int mt = 0; mt < 2; ++mt)
#pragma unroll
    for (int nt = 0; nt < 8; ++nt) acc[mt][nt] = (f32x4){0.f, 0.f, 0.f, 0.f};

  const int ar = t >> 2, aoff = t & 3;

  for (int kc = 0; kc < 4; ++kc) {
    const int h0 = kc * 32;
    *(short8*)&AL[ar * 40 + aoff * 8] =
        *(const short8*)&cT[(b * C_ + c0 + ar) * H_ + h0 + aoff * 8];
    *(short8*)&AL[(64 + ar) * 40 + aoff * 8] =
        *(const short8*)&cT[(b * C_ + c0 + 64 + ar) * H_ + h0 + aoff * 8];
    *(short8*)&BL[ar * 40 + aoff * 8] =
        *(const short8*)&qTw[(b * Q_ + ar) * H_ + h0 + aoff * 8];
    *(short8*)&BL[(64 + ar) * 40 + aoff * 8] =
        *(const short8*)&qTw[(b * Q_ + 64 + ar) * H_ + h0 + aoff * 8];
    __syncthreads();
    bf16x8 af0 = *(bf16x8*)&AL[(w * 32 + lcol) * 40 + quad * 8];
    bf16x8 af1 = *(bf16x8*)&AL[(w * 32 + 16 + lcol) * 40 + quad * 8];
#pragma unroll
    for (int nt = 0; nt < 8; ++nt) {
      bf16x8 bfrag = *(bf16x8*)&BL[(nt * 16 + lcol) * 40 + quad * 8];
      acc[0][nt] = __builtin_amdgcn_mfma_f32_16x16x32_bf16(af0, bfrag, acc[0][nt], 0, 0, 0);
      acc[1][nt] = __builtin_amdgcn_mfma_f32_16x16x32_bf16(af1, bfrag, acc[1][nt], 0, 0, 0);
    }
    __syncthreads();
  }

  float s1v[8];
#pragma unroll
  for (int nt = 0; nt < 8; ++nt) s1v[nt] = s1mL[nt * 16 + lcol];
  float cs0[2][4];
#pragma unroll
  for (int mt = 0; mt < 2; ++mt)
#pragma unroll
    for (int r = 0; r < 4; ++r)
      cs0[mt][r] = scolL[w * 32 + mt * 16 + quad * 4 + r];

  // ---- row max ----
  float rm[2][4];
#pragma unroll
  for (int mt = 0; mt < 2; ++mt)
#pragma unroll
    for (int r = 0; r < 4; ++r) {
      float m = -INFINITY;
#pragma unroll
      for (int nt = 0; nt < 8; ++nt) m = fmaxf(m, acc[mt][nt][r] + s1v[nt]);
      rm[mt][r] = m;
    }
#pragma unroll
  for (int d = 1; d <= 8; d <<= 1)
#pragma unroll
    for (int mt = 0; mt < 2; ++mt)
#pragma unroll
      for (int r = 0; r < 4; ++r)
        rm[mt][r] = fmaxf(rm[mt][r], __shfl_xor(rm[mt][r], d));

  // ---- col partial max from RAW logits (before acc overwrite) ----
  float pmv[8];
#pragma unroll
  for (int nt = 0; nt < 8; ++nt) {
    float m = -INFINITY;
#pragma unroll
    for (int mt = 0; mt < 2; ++mt)
#pragma unroll
      for (int r = 0; r < 4; ++r) m = fmaxf(m, acc[mt][nt][r] + cs0[mt][r]);
    pmv[nt] = m;
  }
#pragma unroll
  for (int nt = 0; nt < 8; ++nt) {
    pmv[nt] = fmaxf(pmv[nt], __shfl_xor(pmv[nt], 16));
    pmv[nt] = fmaxf(pmv[nt], __shfl_xor(pmv[nt], 32));
  }
  if (l < 16) {
#pragma unroll
    for (int nt = 0; nt < 8; ++nt) pw[w * 128 + nt * 16 + lcol] = pmv[nt];
  }

  // ---- overwrite acc with row-exp (computed ONCE) ----
#pragma unroll
  for (int mt = 0; mt < 2; ++mt)
#pragma unroll
    for (int nt = 0; nt < 8; ++nt)
#pragma unroll
      for (int r = 0; r < 4; ++r)
        acc[mt][nt][r] = __expf(acc[mt][nt][r] + s1v[nt] - rm[mt][r]);

  // ---- row sums -> inverse ----
  float inv[2][4];
#pragma unroll
  for (int mt = 0; mt < 2; ++mt)
#pragma unroll
    for (int r = 0; r < 4; ++r) {
      float s = 0.f;
#pragma unroll
      for (int nt = 0; nt < 8; ++nt) s += acc[mt][nt][r];
      inv[mt][r] = s;
    }
#pragma unroll
  for (int d = 1; d <= 8; d <<= 1)
#pragma unroll
    for (int mt = 0; mt < 2; ++mt)
#pragma unroll
      for (int r = 0; r < 4; ++r)
        inv[mt][r] += __shfl_xor(inv[mt][r], d);
#pragma unroll
  for (int mt = 0; mt < 2; ++mt)
#pragma unroll
    for (int r = 0; r < 4; ++r) inv[mt][r] = 1.f / inv[mt][r];

  // repack normalized a_att -> RP[c][q]  (no exp recompute: acc holds rowexp)
#pragma unroll
  for (int mt = 0; mt < 2; ++mt)
#pragma unroll
    for (int nt = 0; nt < 8; ++nt)
#pragma unroll
      for (int r = 0; r < 4; ++r) {
        int row = w * 32 + mt * 16 + quad * 4 + r;
        int col = nt * 16 + lcol;
        RP[row * 136 + col] = f2bs(acc[mt][nt][r] * inv[mt][r]);
      }
  __syncthreads();  // (B)
  {
    const int row = t >> 1, half = t & 1;
    short* dst = a_att + (b * C_ + c0 + row) * Q_ + half * 64;
    const short* srcp = RP + row * 136 + half * 64;
#pragma unroll
    for (int j = 0; j < 8; ++j) *(short8*)&dst[j * 8] = *(const short8*)&srcp[j * 8];
  }
  __syncthreads();  // (C)
  if (t < 128) {
    float m = fmaxf(fmaxf(pw[t], pw[128 + t]), fmaxf(pw[256 + t], pw[384 + t]));
    mpL[t] = m;
    pcm[(b * 8 + bx) * Q_ + t] = m;
  }
  __syncthreads();  // (D)
  float mpv[8];
#pragma unroll
  for (int nt = 0; nt < 8; ++nt) mpv[nt] = mpL[nt * 16 + lcol];

  // ---- col sums + eP repack fused; colval = rowexp * exp(crm - sm) ----
  float crm[2][4];
#pragma unroll
  for (int mt = 0; mt < 2; ++mt)
#pragma unroll
    for (int r = 0; r < 4; ++r) crm[mt][r] = cs0[mt][r] + rm[mt][r];
  float psv[8];
#pragma unroll
  for (int nt = 0; nt < 8; ++nt) {
    const float sm = s1v[nt] + mpv[nt];
    const int qq = nt * 16 + lcol;
    float s = 0.f;
#pragma unroll
    for (int mt = 0; mt < 2; ++mt)
#pragma unroll
      for (int r = 0; r < 4; ++r) {
        float v = acc[mt][nt][r] * __expf(crm[mt][r] - sm);
        s += v;
        RP[qq * 136 + (w * 32 + mt * 16 + quad * 4 + r)] = f2bs(v);
      }
    psv[nt] = s;
  }
#pragma unroll
  for (int nt = 0; nt < 8; ++nt) {
    psv[nt] += __shfl_xor(psv[nt], 16);
    psv[nt] += __shfl_xor(psv[nt], 32);
  }
  if (l < 16) {
#pragma unroll
    for (int nt = 0; nt < 8; ++nt) pw[w * 128 + nt * 16 + lcol] = psv[nt];
  }
  __syncthreads();  // (E) — also orders all RP eP-writes before stores below
  if (t < 128) pcs[(b * 8 + bx) * Q_ + t] = pw[t] + pw[128 + t] + pw[256 + t] + pw[384 + t];
  {
    const int qq = t >> 1, half = t & 1;
    short* dst = ePT + (b * Q_ + qq) * C_ + c0 + half * 64;
    const short* srcp = RP + qq * 136 + half * 64;
#pragma unroll
    for (int j = 0; j < 8; ++j) *(short8*)&dst[j * 8] = *(const short8*)&srcp[j * 8];
  }
}

// ---------------------------------------------------------------------------
// k3: Tpart[kc][b][h][q] = inv_cs[q] * sum_{c in kc-chunk} scale*eP[q][c]*c[h][c].
// Fuses old k2b (scale/inv recompute from pcm/pcs, L2-hot) and krs (A-load
// scaling) — kills a 32MB R/W pass and two dispatches.
// grid (2 hb, 4 kc, B), block 256.
// ---------------------------------------------------------------------------
__global__ __launch_bounds__(256) void k3_T(
    const short* __restrict__ ePT, const float* __restrict__ cin,
    const float* __restrict__ pcm, const float* __restrict__ pcs,
    float* __restrict__ Tpart) {
  __shared__ __align__(16) char uni[34816];
  short* AL = (short*)uni;            // [128][40]
  short* BL = (short*)(uni + 10240);  // [64][40]
  float* RPF = (float*)uni;           // [64][136] f32 (after K-loop)
  __shared__ float scA[2][128];       // per-q scale for this block's 2 c-tiles
  __shared__ float icL[128];          // per-q 1/colsum
  const int t = threadIdx.x;
  const int w = t >> 6, l = t & 63, quad = l >> 4, lcol = l & 15;
  const int hb = blockIdx.x * 64, kc = blockIdx.y, b = blockIdx.z;

  if (t < 128) {  // in-block k2b: combine 8 column partials for this b
    float m[8]; float M = -INFINITY;
#pragma unroll
    for (int k = 0; k < 8; ++k) { m[k] = pcm[(b * 8 + k) * Q_ + t]; M = fmaxf(M, m[k]); }
    float s = 0.f;
#pragma unroll
    for (int k = 0; k < 8; ++k) s += pcs[(b * 8 + k) * Q_ + t] * __expf(m[k] - M);
    icL[t] = 1.f / s;
    scA[0][t] = __expf(m[kc * 2 + 0] - M);
    scA[1][t] = __expf(m[kc * 2 + 1] - M);
  }

  f32x4 acc[2][4];
#pragma unroll
  for (int mt = 0; mt < 2; ++mt)
#pragma unroll
    for (int nt = 0; nt < 4; ++nt) acc[mt][nt] = (f32x4){0.f, 0.f, 0.f, 0.f};

  const int ar = t >> 2, aoff = t & 3;
  __syncthreads();  // scA/icL ready
  const float s00 = scA[0][ar], s01 = scA[0][64 + ar];
  const float s10 = scA[1][ar], s11 = scA[1][64 + ar];

  for (int ck = 0; ck < 8; ++ck) {
    const int coff = kc * 256 + ck * 32;
    const float sA0 = (ck < 4) ? s00 : s10;
    const float sA1 = (ck < 4) ? s01 : s11;
    {
      short8 v0 = *(const short8*)&ePT[(b * Q_ + ar) * C_ + coff + aoff * 8];
      short8 v1 = *(const short8*)&ePT[(b * Q_ + 64 + ar) * C_ + coff + aoff * 8];
      short8 o0, o1;
#pragma unroll
      for (int i = 0; i < 8; ++i) {
        o0[i] = f2bs(bs2f(v0[i]) * sA0);
        o1[i] = f2bs(bs2f(v1[i]) * sA1);
      }
      *(short8*)&AL[ar * 40 + aoff * 8] = o0;
      *(short8*)&AL[(64 + ar) * 40 + aoff * 8] = o1;
    }
    {
      const float* srcp = cin + (b * H_ + hb + ar) * C_ + coff + aoff * 8;
      short8 o;
#pragma unroll
      for (int i = 0; i < 8; ++i) o[i] = f2bs(srcp[i]);
      *(short8*)&BL[ar * 40 + aoff * 8] = o;
    }
    __syncthreads();
    bf16x8 af0 = *(bf16x8*)&AL[(w * 32 + lcol) * 40 + quad * 8];
    bf16x8 af1 = *(bf16x8*)&AL[(w * 32 + 16 + lcol) * 40 + quad * 8];
#pragma unroll
    for (int nt = 0; nt < 4; ++nt) {
      bf16x8 bfrag = *(bf16x8*)&BL[(nt * 16 + lcol) * 40 + quad * 8];
      acc[0][nt] = __builtin_amdgcn_mfma_f32_16x16x32_bf16(af0, bfrag, acc[0][nt], 0, 0, 0);
      acc[1][nt] = __builtin_amdgcn_mfma_f32_16x16x32_bf16(af1, bfrag, acc[1][nt], 0, 0, 0);
    }
    __syncthreads();
  }
  // RPF[h-local][q], then coalesced f32 stores with inv_cs folded in
#pragma unroll
  for (int mt = 0; mt < 2; ++mt)
#pragma unroll
    for (int nt = 0; nt < 4; ++nt)
#pragma unroll
      for (int r = 0; r < 4; ++r)
        RPF[(nt * 16 + lcol) * 136 + (w * 32 + mt * 16 + quad * 4 + r)] = acc[mt][nt][r];
  __syncthreads();
  {
    float* Tp = Tpart + (size_t)kc * (B_ * H_ * Q_) + ((size_t)b * H_ + hb) * Q_;
    const int lr = t >> 5, coln = (t & 31) * 4;
    float4 ic = *(const float4*)&icL[coln];
#pragma unroll
    for (int iter = 0; iter < 8; ++iter) {
      int hl = iter * 8 + lr;
      float4 v = *(float4*)&RPF[hl * 136 + coln];
      v.x *= ic.x; v.y *= ic.y; v.z *= ic.z; v.w *= ic.w;
      *(float4*)&Tp[hl * Q_ + coln] = v;
    }
  }
}

// ---------------------------------------------------------------------------
// k3b: TmT[b][h][q] (bf16) = sum of 4 (pre-normalized) partials. grid 1024, 256.
// ---------------------------------------------------------------------------
__global__ __launch_bounds__(256) void k3b(const float* __restrict__ Tpart,
                                           short* __restrict__ TmT) {
  const int gid = blockIdx.x * 256 + threadIdx.x;
  const int e = gid * 4;
  float4 s = make_float4(0.f, 0.f, 0.f, 0.f);
#pragma unroll
  for (int k = 0; k < 4; ++k) {
    float4 v = *(const float4*)&Tpart[(size_t)k * (B_ * H_ * Q_) + e];
    s.x += v.x; s.y += v.y; s.z += v.z; s.w += v.w;
  }
  short4s o;
  o[0] = f2bs(s.x); o[1] = f2bs(s.y); o[2] = f2bs(s.z); o[3] = f2bs(s.w);
  *(short4s*)&TmT[e] = o;
}

// ---------------------------------------------------------------------------
// k4: a = a_att@qT, b = a_att@Tm (MFMA); emit [c, a, c*a, c*b].
// grid (8, 2, B), block 256. Non-temporal coalesced row-major stores.
// ---------------------------------------------------------------------------
__global__ __launch_bounds__(256) void k4_out(
    const short* __restrict__ a_att, const short* __restrict__ qbf,
    const short* __restrict__ TmT, const float* __restrict__ cin,
    float* __restrict__ out) {
  __shared__ __align__(16) char uni[34816];
  short* AL = (short*)uni;             // [128][40]
  short* B1 = (short*)(uni + 10240);   // [64][40]
  short* B2 = (short*)(uni + 15360);   // [64][40]
  float* RPF = (float*)uni;            // [64][136] f32
  const int t = threadIdx.x;
  const int w = t >> 6, l = t & 63, quad = l >> 4, lcol = l & 15;
  const int c0 = blockIdx.x * 128, hb = blockIdx.y * 64, b = blockIdx.z;

  f32x4 accA[2][4], accB[2][4];
#pragma unroll
  for (int mt = 0; mt < 2; ++mt)
#pragma unroll
    for (int nt = 0; nt < 4; ++nt) {
      accA[mt][nt] = (f32x4){0.f, 0.f, 0.f, 0.f};
      accB[mt][nt] = (f32x4){0.f, 0.f, 0.f, 0.f};
    }

  const int ar = t >> 2, aoff = t & 3;
  for (int kc = 0; kc < 4; ++kc) {
    const int q0 = kc * 32;
    *(short8*)&AL[ar * 40 + aoff * 8] =
        *(const short8*)&a_att[(b * C_ + c0 + ar) * Q_ + q0 + aoff * 8];
    *(short8*)&AL[(64 + ar) * 40 + aoff * 8] =
        *(const short8*)&a_att[(b * C_ + c0 + 64 + ar) * Q_ + q0 + aoff * 8];
    *(short8*)&B1[ar * 40 + aoff * 8] =
        *(const short8*)&qbf[(b * H_ + hb + ar) * Q_ + q0 + aoff * 8];
    *(short8*)&B2[ar * 40 + aoff * 8] =
        *(const short8*)&TmT[(b * H_ + hb + ar) * Q_ + q0 + aoff * 8];
    __syncthreads();
    bf16x8 af0 = *(bf16x8*)&AL[(w * 32 + lcol) * 40 + quad * 8];
    bf16x8 af1 = *(bf16x8*)&AL[(w * 32 + 16 + lcol) * 40 + quad * 8];
#pragma unroll
    for (int nt = 0; nt < 4; ++nt) {
      bf16x8 bq = *(bf16x8*)&B1[(nt * 16 + lcol) * 40 + quad * 8];
      bf16x8 bt = *(bf16x8*)&B2[(nt * 16 + lcol) * 40 + quad * 8];
      accA[0][nt] = __builtin_amdgcn_mfma_f32_16x16x32_bf16(af0, bq, accA[0][nt], 0, 0, 0);
      accA[1][nt] = __builtin_amdgcn_mfma_f32_16x16x32_bf16(af1, bq, accA[1][nt], 0, 0, 0);
      accB[0][nt] = __builtin_amdgcn_mfma_f32_16x16x32_bf16(af0, bt, accB[0][nt], 0, 0, 0);
      accB[1][nt] = __builtin_amdgcn_mfma_f32_16x16x32_bf16(af1, bt, accB[1][nt], 0, 0, 0);
    }
    __syncthreads();
  }

  const int lr = t >> 5, coln = (t & 31) * 4;
  float* ob = out + (size_t)b * 512 * 1024;
  float4 cvv[8];

  // pass A: slabs c, a, c*a  (coalesced: 32 lanes cover one 512B row)
#pragma unroll
  for (int mt = 0; mt < 2; ++mt)
#pragma unroll
    for (int nt = 0; nt < 4; ++nt)
#pragma unroll
      for (int r = 0; r < 4; ++r)
        RPF[(nt * 16 + lcol) * 136 + (w * 32 + mt * 16 + quad * 4 + r)] = accA[mt][nt][r];
  __syncthreads();
#pragma unroll
  for (int iter = 0; iter < 8; ++iter) {
    int hl = iter * 8 + lr;
    int hrow = hb + hl;
    float4 la = *(float4*)&RPF[hl * 136 + coln];
    float4 cv = *(const float4*)&cin[(b * H_ + hrow) * C_ + c0 + coln];
    cvv[iter] = cv;
    nts4(&ob[(size_t)hrow * 1024 + c0 + coln], cv);
    nts4(&ob[(size_t)(128 + hrow) * 1024 + c0 + coln], la);
    float4 p = make_float4(cv.x * la.x, cv.y * la.y, cv.z * la.z, cv.w * la.w);
    nts4(&ob[(size_t)(256 + hrow) * 1024 + c0 + coln], p);
  }
  __syncthreads();
  // pass B: slab c*b
#pragma unroll
  for (int mt = 0; mt < 2; ++mt)
#pragma unroll
    for (int nt = 0; nt < 4; ++nt)
#pragma unroll
      for (int r = 0; r < 4; ++r)
        RPF[(nt * 16 + lcol) * 136 + (w * 32 + mt * 16 + quad * 4 + r)] = accB[mt][nt][r];
  __syncthreads();
#pragma unroll
  for (int iter = 0; iter < 8; ++iter) {
    int hl = iter * 8 + lr;
    int hrow = hb + hl;
    float4 lb = *(float4*)&RPF[hl * 136 + coln];
    float4 cv = cvv[iter];
    float4 p = make_float4(cv.x * lb.x, cv.y * lb.y, cv.z * lb.z, cv.w * lb.w);
    nts4(&ob[(size_t)(384 + hrow) * 1024 + c0 + coln], p);
  }
}

// ---------------------------------------------------------------------------
extern "C" void kernel_launch(void* const* d_in, const int* in_sizes, int n_in,
                              void* d_out, int out_size, void* d_ws, size_t ws_size,
                              hipStream_t stream) {
  const float* c     = (const float*)d_in[0];
  const float* q     = (const float*)d_in[1];
  const float* cmask = (const float*)d_in[2];
  const float* qmask = (const float*)d_in[3];
  const float* ctxw  = (const float*)d_in[4];
  const float* qw    = (const float*)d_in[5];
  const float* cqw   = (const float*)d_in[6];
  float* out = (float*)d_out;

  char* ws = (char*)d_ws;
  short* cT     = (short*)(ws);                       // 16,777,216 B (k1 input)
  float* Tpart  = (float*)(ws);                       // alias: cT dead after k1
  short* qTw    = (short*)(ws + 16777216);            //  2,097,152 B (k1 input)
  short* TmT    = (short*)(ws + 16777216);            // alias: qTw dead after k1
  short* qbf    = (short*)(ws + 18874368);            //  2,097,152 B
  short* a_att  = (short*)(ws + 20971520);            // 16,777,216 B
  short* ePT    = (short*)(ws + 37748736);            // 16,777,216 B
  float* s0p    = (float*)(ws + 54525952);            //    524,288 B
  float* s1m    = (float*)(ws + 55050240);            //     32,768 B
  float* pcm    = (float*)(ws + 55083008);            //    262,144 B
  float* pcs    = (float*)(ws + 55345152);            //    262,144 B

  kTc<<<dim3(16, 2, B_), dim3(256), 0, stream>>>(c, ctxw, cT, s0p);
  kq<<<dim3(2, B_), dim3(256), 0, stream>>>(q, qw, cqw, qmask, qTw, qbf, s1m);
  k1_mfma<<<dim3(8, B_), dim3(256), 0, stream>>>(cT, qTw, s1m, cmask, s0p,
                                                 a_att, ePT, pcm, pcs);
  k3_T<<<dim3(2, 4, B_), dim3(256), 0, stream>>>(ePT, c, pcm, pcs, Tpart);
  k3b<<<dim3(1024), dim3(256), 0, stream>>>(Tpart, TmT);
  k4_out<<<dim3(8, 2, B_), dim3(256), 0, stream>>>(a_att, qbf, TmT, c, out);
}